// Round 9
// baseline (242.421 us; speedup 1.0000x reference)
//
#include <hip/hip_runtime.h>
#include <hip/hip_bf16.h>
#include <stdint.h>

#define NB 2
#define NS 4096
#define ND 768
#define NH 12
#define NW 128
#define NDFF 3072
#define NHD 64
#define NCH 32   // NS/NW

typedef __attribute__((ext_vector_type(8))) short bf16x8;
typedef __attribute__((ext_vector_type(4))) short s16x4;
typedef __attribute__((ext_vector_type(4))) float f32x4;
typedef __attribute__((ext_vector_type(4))) int i32x4;

__device__ __forceinline__ float bf2f(short u) {
    union { unsigned int i; float f; } c;
    c.i = ((unsigned int)(unsigned short)u) << 16;
    return c.f;
}
__device__ __forceinline__ short f2bf(float f) {
    union { float f; unsigned int i; } c;
    c.f = f;
    unsigned int x = c.i;
    return (short)((x + 0x7fffu + ((x >> 16) & 1u)) >> 16);
}
__device__ __forceinline__ unsigned int cvtpk(float lo, float hi) {
    unsigned int r;
    asm("v_cvt_pk_bf16_f32 %0, %1, %2" : "=v"(r) : "v"(lo), "v"(hi));
    return r;
}
__device__ __forceinline__ float ubits_lo(unsigned u) {
    union { unsigned i; float f; } c; c.i = u << 16; return c.f;
}
__device__ __forceinline__ float ubits_hi(unsigned u) {
    union { unsigned i; float f; } c; c.i = u & 0xffff0000u; return c.f;
}

__device__ __forceinline__ void gl16(const void* g, const void* l) {
    __builtin_amdgcn_global_load_lds(
        (const __attribute__((address_space(1))) void*)g,
        (__attribute__((address_space(3))) void*)l, 16, 0, 0);
}

// ---------------- cast f32 -> bf16 (vectorized) ----------------
__global__ __launch_bounds__(256) void cast_bf16(const float* __restrict__ in,
                                                 short* __restrict__ out, int n4) {
    int i = blockIdx.x * 256 + threadIdx.x;
    if (i < n4) {
        f32x4 v = ((const f32x4*)in)[i];
        s16x4 o;
        o[0] = f2bf(v[0]); o[1] = f2bf(v[1]); o[2] = f2bf(v[2]); o[3] = f2bf(v[3]);
        ((s16x4*)out)[i] = o;
    }
}

// ---------------- transpose + cast: in[K][N] f32 -> out[N][K] bf16 ----------------
__global__ __launch_bounds__(256) void transpose_cast(const float* __restrict__ in,
                                                      short* __restrict__ out,
                                                      int K, int N) {
    __shared__ float tile[32][33];
    int kb = blockIdx.y * 32, nb = blockIdx.x * 32;
    int tx = threadIdx.x & 31, ty = threadIdx.x >> 5;   // ty 0..7
    #pragma unroll
    for (int r = ty; r < 32; r += 8)
        tile[r][tx] = in[(long)(kb + r) * N + nb + tx];
    __syncthreads();
    #pragma unroll
    for (int r = ty; r < 32; r += 8)
        out[(long)(nb + r) * K + kb + tx] = f2bf(tile[tx][r]);
}

// ======== 256x256 8-phase pipelined GEMM (T2+T3+T4+T5): C = A @ Bt^T ========
// BK=64, 2 LDS dbufs of 64KB (A-lo/A-hi/B-lo/B-hi half-tiles, 16KB each),
// per-row XOR chunk swizzle (both-sides involution, verified conflict-free R3/R4),
// 8 phases/iter over 2 K-tiles; stage 1 half-tile per phase; counted vmcnt(2)
// only at phases 3 and 7. 8 waves (2M x 4N), wave tile 128x64, acc[8][4].
// MODE 4: fused QKV epilogue; MODE 2: relu->bf16 [M][NDFF].
#define GPH(BUF, MB, KK, STMT, WT)                                            \
    {                                                                          \
        const char* db = smem + (BUF) * 65536;                                 \
        if ((MB) == 0) {                                                       \
            bfr[0] = *(const bf16x8*)(db + boff + 0 * 2048 + pk##KK);          \
            bfr[1] = *(const bf16x8*)(db + boff + 1 * 2048 + pk##KK);          \
            bfr[2] = *(const bf16x8*)(db + boff + 2 * 2048 + pk##KK);          \
            bfr[3] = *(const bf16x8*)(db + boff + 3 * 2048 + pk##KK);          \
        }                                                                      \
        af[0] = *(const bf16x8*)(db + aoff + ((MB) + 0) * 2048 + pk##KK);      \
        af[1] = *(const bf16x8*)(db + aoff + ((MB) + 1) * 2048 + pk##KK);      \
        af[2] = *(const bf16x8*)(db + aoff + ((MB) + 2) * 2048 + pk##KK);      \
        af[3] = *(const bf16x8*)(db + aoff + ((MB) + 3) * 2048 + pk##KK);      \
        STMT;                                                                  \
        __builtin_amdgcn_s_barrier();                                          \
        asm volatile("s_waitcnt lgkmcnt(0)" ::: "memory");                     \
        __builtin_amdgcn_s_setprio(1);                                         \
        _Pragma("unroll")                                                      \
        for (int mm = 0; mm < 4; ++mm)                                         \
            _Pragma("unroll")                                                  \
            for (int nn = 0; nn < 4; ++nn)                                     \
                acc[(MB) + mm][nn] = __builtin_amdgcn_mfma_f32_16x16x32_bf16(  \
                    af[mm], bfr[nn], acc[(MB) + mm][nn], 0, 0, 0);             \
        __builtin_amdgcn_s_setprio(0);                                         \
        WT;                                                                    \
        __builtin_amdgcn_s_barrier();                                          \
    }

template<int MODE>
__global__ __launch_bounds__(512, 2) void gemm8p(
    const short* __restrict__ A,
    const short* __restrict__ Bt,
    const float* __restrict__ b0,
    const float* __restrict__ b1,
    const float* __restrict__ b2,
    void* __restrict__ outp,
    int M, int N, int K, int gx)
{
    extern __shared__ char smem[];   // 131072 B
    const int KT = K >> 6;
    int cpx = gridDim.x >> 3;
    int bid = blockIdx.x;
    int tile = (bid & 7) * cpx + (bid >> 3);
    int n0 = (tile % gx) * 256;
    int m0 = (tile / gx) * 256;
    int tid = threadIdx.x;
    int wid = tid >> 6, lane = tid & 63;
    int wm = wid >> 2, wn = wid & 3;          // 2M x 4N, wave tile 128x64
    int g = lane >> 4, lr = lane & 15;

    // staging: chunks c = tid, tid+512; r = c>>3, phys chunk = c&7,
    // logical chunk = (c&7) ^ (r&7)  (both-sides XOR involution)
    int r0s = tid >> 3;
    int lc0 = (tid & 7) ^ (r0s & 7);
    int r1s = r0s + 64;
    int lc1 = (tid & 7) ^ (r1s & 7);
    const short* pA0 = A + (long)(m0 + r0s) * K + lc0 * 8;
    const short* pA1 = A + (long)(m0 + r1s) * K + lc1 * 8;
    const short* pB0 = Bt + (long)(n0 + r0s) * K + lc0 * 8;
    const short* pB1 = Bt + (long)(n0 + r1s) * K + lc1 * 8;
    const long hstep = (long)128 * K;

    f32x4 acc[8][4];
    #pragma unroll
    for (int a = 0; a < 8; ++a)
        #pragma unroll
        for (int c = 0; c < 4; ++c)
            acc[a][c] = (f32x4){0.f, 0.f, 0.f, 0.f};
    bf16x8 af[4], bfr[4];

    // fragment read bases (bytes): A half = wm; B half = wn>>1
    int aoff = wm * 16384 + lr * 128;
    int boff = 32768 + (wn >> 1) * 16384 + ((wn & 1) * 64 + lr) * 128;
    int pk0 = (g ^ (lr & 7)) << 4;
    int pk1 = ((4 + g) ^ (lr & 7)) << 4;

    auto stg = [&](int kt, int isB, int half) {
        char* l = smem + (kt & 1) * 65536 + isB * 32768 + half * 16384 + tid * 16;
        long off = (long)half * hstep + ((long)kt << 6);
        if (isB) {
            gl16(pB0 + off, l);
            gl16(pB1 + off, l + 8192);
        } else {
            gl16(pA0 + off, l);
            gl16(pA1 + off, l + 8192);
        }
    };

    // prologue: t0 fully (Blo,Bhi,Alo,Ahi) + t1:Blo; wait t0 (2 loads may fly)
    stg(0, 1, 0); stg(0, 1, 1); stg(0, 0, 0); stg(0, 0, 1);
    stg(1, 1, 0);
    asm volatile("s_waitcnt vmcnt(2)" ::: "memory");
    __builtin_amdgcn_s_barrier();

    for (int it = 0, t = 0; it < (KT >> 1); ++it, t += 2) {
        bool s2 = (t + 2) < KT, s3 = (t + 3) < KT;
        // ---- tile t (buf 0): phases 0-3 ----
        GPH(0, 0, 0, stg(t + 1, 1, 1), ;)
        GPH(0, 4, 0, stg(t + 1, 0, 0), ;)
        GPH(0, 0, 1, stg(t + 1, 0, 1), ;)
        GPH(0, 4, 1, if (s2) stg(t + 2, 1, 0),
            if (s2) { asm volatile("s_waitcnt vmcnt(2)" ::: "memory"); }
            else    { asm volatile("s_waitcnt vmcnt(0)" ::: "memory"); })
        // ---- tile t+1 (buf 1): phases 4-7 ----
        GPH(1, 0, 0, if (s2) stg(t + 2, 1, 1), ;)
        GPH(1, 4, 0, if (s2) stg(t + 2, 0, 0), ;)
        GPH(1, 0, 1, if (s2) stg(t + 2, 0, 1), ;)
        GPH(1, 4, 1, if (s3) stg(t + 3, 1, 0),
            if (s3) { asm volatile("s_waitcnt vmcnt(2)" ::: "memory"); }
            else    { asm volatile("s_waitcnt vmcnt(0)" ::: "memory"); })
    }

    // ---- epilogue (fragment->C mapping verified in R3) ----
    int mr0 = m0 + wm * 128;
    int nc0 = n0 + wn * 64;
    if (MODE == 4) {
        int proj = n0 / 768;   // 0=q,1=k,2=v (256 | 768, block never straddles)
        const float* bp = (proj == 0) ? b0 : (proj == 1) ? b1 : b2;
        float scl = (proj == 0) ? 0.125f : 1.0f;
        short* obase = (short*)outp + (long)proj * ((long)NB * NS * ND);
        #pragma unroll
        for (int mt = 0; mt < 8; ++mt) {
            #pragma unroll
            for (int nt = 0; nt < 4; ++nt) {
                int c = nc0 + nt * 16 + lr - proj * 768;
                int hh = c >> 6, hd = c & 63;
                float bv = bp[c];
                if (proj == 2) {
                    int m = mr0 + mt * 16 + (g << 2);
                    int bbi = m >> 12, s = m & (NS - 1);
                    s16x4 ov;
                    ov[0] = f2bf(acc[mt][nt][0] + bv);
                    ov[1] = f2bf(acc[mt][nt][1] + bv);
                    ov[2] = f2bf(acc[mt][nt][2] + bv);
                    ov[3] = f2bf(acc[mt][nt][3] + bv);
                    *(s16x4*)&obase[((long)(bbi * NH + hh) * NHD + hd) * NS + s] = ov;
                } else {
                    #pragma unroll
                    for (int i = 0; i < 4; ++i) {
                        int m = mr0 + mt * 16 + (g << 2) + i;
                        int bbi = m >> 12, s = m & (NS - 1);
                        obase[((long)(bbi * NH + hh) * NS + s) * NHD + hd] =
                            f2bf((acc[mt][nt][i] + bv) * scl);
                    }
                }
            }
        }
    } else {   // MODE 2: relu -> bf16 hidden
        #pragma unroll
        for (int mt = 0; mt < 8; ++mt) {
            #pragma unroll
            for (int nt = 0; nt < 4; ++nt) {
                int col = nc0 + nt * 16 + lr;
                float bv = b0[col];
                #pragma unroll
                for (int i = 0; i < 4; ++i) {
                    int m = mr0 + mt * 16 + (g << 2) + i;
                    float v = fmaxf(acc[mt][nt][i] + bv, 0.f);
                    ((short*)outp)[(long)m * NDFF + col] = f2bf(v);
                }
            }
        }
    }
}

// ------------- 128x128 double-buffered GEMM (verified; FFN2 only) -------------
template<int MODE>
__global__ __launch_bounds__(256, 2) void gemmdb(
    const short* __restrict__ A,
    const short* __restrict__ Bt,
    const float* __restrict__ b0,
    void* __restrict__ outp,
    const short* __restrict__ xres,
    int M, int N, int K, int gx)
{
    __shared__ short lds[2][256 * 64];   // per buf: A[128][64] | B[128][64]
    const int KT = K >> 6;

    int cpx = gridDim.x >> 3;
    int bid = blockIdx.x;
    int tile = (bid & 7) * cpx + (bid >> 3);
    int n0 = (tile % gx) * 128;
    int m0 = (tile / gx) * 128;

    int tid = threadIdx.x;
    int wid = tid >> 6, lane = tid & 63;
    int wr = wid >> 1, wc = wid & 1;          // 2x2 waves, wave tile 64x64
    int g = lane >> 4, lr = lane & 15;

    int rl = lane >> 3, sl = lane & 7;
    int soff = (sl ^ rl) << 3;                 // k-element offset (swizzled)
    const short* gA[4];
    const short* gB[4];
    #pragma unroll
    for (int c = 0; c < 4; ++c) {
        int row = c * 32 + wid * 8 + rl;
        gA[c] = A + (long)(m0 + row) * K + soff;
        gB[c] = Bt + (long)(n0 + row) * K + soff;
    }

    f32x4 acc[4][4];
    #pragma unroll
    for (int a = 0; a < 4; ++a)
        #pragma unroll
        for (int c = 0; c < 4; ++c)
            acc[a][c] = (f32x4){0.f, 0.f, 0.f, 0.f};

    auto stage = [&](int t, int buf) {
        long ko = (long)t << 6;
        #pragma unroll
        for (int c = 0; c < 4; ++c) {
            int lbase = (c * 32 + wid * 8) * 64;
            gl16(gA[c] + ko, &lds[buf][lbase]);
            gl16(gB[c] + ko, &lds[buf][128 * 64 + lbase]);
        }
    };

    stage(0, 0);
    asm volatile("s_waitcnt vmcnt(0)" ::: "memory");
    __builtin_amdgcn_s_barrier();

    int buf = 0;
    for (int t = 0; t < KT; ++t) {
        if (t + 1 < KT) stage(t + 1, buf ^ 1);
        const short* bufA = lds[buf];
        const short* bufB = lds[buf] + 128 * 64;
        bf16x8 af[2][4], bfr[2][4];
        #pragma unroll
        for (int kk = 0; kk < 2; ++kk) {
            int ph = (((kk << 2) + g) ^ (lr & 7)) << 3;   // swizzled k-slot (elems)
            #pragma unroll
            for (int mt = 0; mt < 4; ++mt)
                af[kk][mt] = *(const bf16x8*)&bufA[(wr * 64 + mt * 16 + lr) * 64 + ph];
            #pragma unroll
            for (int nt = 0; nt < 4; ++nt)
                bfr[kk][nt] = *(const bf16x8*)&bufB[(wc * 64 + nt * 16 + lr) * 64 + ph];
        }
        #pragma unroll
        for (int kk = 0; kk < 2; ++kk)
            #pragma unroll
            for (int mt = 0; mt < 4; ++mt)
                #pragma unroll
                for (int nt = 0; nt < 4; ++nt)
                    acc[mt][nt] = __builtin_amdgcn_mfma_f32_16x16x32_bf16(
                        af[kk][mt], bfr[kk][nt], acc[mt][nt], 0, 0, 0);
        asm volatile("s_waitcnt vmcnt(0)" ::: "memory");
        __builtin_amdgcn_s_barrier();
        buf ^= 1;
    }

    int mr0 = m0 + wr * 64;
    int nc0 = n0 + wc * 64;
    #pragma unroll
    for (int mt = 0; mt < 4; ++mt) {
        #pragma unroll
        for (int nt = 0; nt < 4; ++nt) {
            int col = nc0 + nt * 16 + lr;
            float bv = b0[col];
            #pragma unroll
            for (int i = 0; i < 4; ++i) {
                int m = mr0 + mt * 16 + (g << 2) + i;
                float v = acc[mt][nt][i] + bv + bf2f(xres[(long)m * ND + col]);
                ((float*)outp)[(long)m * ND + col] = v;
            }
        }
    }
}

// ------- band attention (unchanged from R8 — verified) -------
__global__ __launch_bounds__(512, 2) void attn_kernel(
    const short* __restrict__ qg,   // (B,H,S,HD) bf16, pre-scaled
    const short* __restrict__ kg,   // (B,H,S,HD) bf16
    const short* __restrict__ vtg,  // (B,H,HD,S) bf16
    const float* __restrict__ src,  // (B,S,D) f32
    float* __restrict__ attw,       // (B,H,S,257) f32
    short* __restrict__ xb)         // (B,S,D) bf16
{
    __shared__ short kvs[384 * 64];   // 48KB: K [384][64] -> later V [64][384]

    int blk = blockIdx.x;
    int ch = blk & 31;
    int tmp = blk >> 5;
    int h = tmp % NH;
    int b = tmp / NH;
    int tid = threadIdx.x;
    int wid = tid >> 6;
    int lane = tid & 63;
    int g = lane >> 4, lr = lane & 15;
    long bh = (long)(b * NH + h);
    long kbase = bh * NS * NHD;
    int srow0 = ch * NW;
    int t0 = wid << 4;
    int tl = t0 + lr;                 // this lane's q-row (local)

    {
        int rsub = lane >> 3;
        int pc = lane & 7;
        int lc = pc ^ rsub;
        #pragma unroll
        for (int i = 0; i < 6; ++i) {
            int inst = wid * 6 + i;
            int j = inst * 8 + rsub;
            int s = srow0 - NW + j;
            s = s < 0 ? 0 : (s >= NS ? NS - 1 : s);
            gl16(&kg[kbase + (long)s * NHD + lc * 8], &kvs[inst * 512 + lane * 8]);
        }
    }
    bf16x8 aq[2];
    #pragma unroll
    for (int kk = 0; kk < 2; ++kk)
        aq[kk] = *(const bf16x8*)&qg[kbase + (long)(srow0 + tl) * NHD + (kk << 5) + (g << 3)];

    asm volatile("s_waitcnt vmcnt(0)" ::: "memory");
    __builtin_amdgcn_s_barrier();
    __builtin_amdgcn_sched_barrier(0);

    unsigned pku0[12][2], pku1[12][2];
    float m0, s0, m1, s1;
    auto half_pass = [&](int jtb, unsigned (&pk)[12][2], float& mh, float& sh) {
        f32x4 sc[12];
        #pragma unroll
        for (int q = 0; q < 12; ++q) {
            int jt = jtb + q;
            f32x4 a = (f32x4){0.f, 0.f, 0.f, 0.f};
            #pragma unroll
            for (int kk = 0; kk < 2; ++kk) {
                int phys = (((kk << 2) + g) ^ (lr & 7)) << 3;
                bf16x8 bk = *(const bf16x8*)&kvs[(jt * 16 + lr) * 64 + phys];
                a = __builtin_amdgcn_mfma_f32_16x16x32_bf16(bk, aq[kk], a, 0, 0, 0);
            }
            sc[q] = a;
        }
        float mx = -3.0e30f;
        #pragma unroll
        for (int q = 0; q < 12; ++q) {
            int j0 = (jtb + q) * 16 + (g << 2);
            #pragma unroll
            for (int i = 0; i < 4; ++i) {
                int j = j0 + i;
                int sp = srow0 - NW + j;
                bool ok = (sp >= 0) && (sp < NS) && (j >= tl) && (j <= tl + 2 * NW);
                float v = ok ? sc[q][i] : -3.0e30f;
                sc[q][i] = v;
                mx = fmaxf(mx, v);
            }
        }
        mx = fmaxf(mx, __shfl_xor(mx, 16, 64));
        mx = fmaxf(mx, __shfl_xor(mx, 32, 64));
        float sm = 0.f;
        #pragma unroll
        for (int q = 0; q < 12; ++q) {
            #pragma unroll
            for (int i = 0; i < 4; ++i) {
                float v = sc[q][i];
                float p = (v > -1.0e30f) ? __expf(v - mx) : 0.0f;
                sc[q][i] = p;
                sm += p;
            }
            pk[q][0] = cvtpk(sc[q][0], sc[q][1]);
            pk[q][1] = cvtpk(sc[q][2], sc[q][3]);
        }
        sm += __shfl_xor(sm, 16, 64);
        sm += __shfl_xor(sm, 32, 64);
        mh = mx; sh = sm;
    };

    auto stageV = [&](int hf) {
        #pragma unroll
        for (int i = 0; i < 3; ++i) {
            int v = wid * 3 + i;
            int fc = hf * 1536 + v * 64 + lane;
            int hd = fc / 48;
            int pc = fc % 48;
            int lc = (pc & ~7) | ((pc & 7) ^ (hd & 7));
            int scol = srow0 - NW + lc * 8;
            scol = scol < 0 ? 0 : (scol > NS - 8 ? NS - 8 : scol);
            gl16(&vtg[(bh * NHD + hd) * NS + scol],
                 &kvs[hf * 12288 + v * 512 + lane * 8]);
        }
    };

    half_pass(0, pku0, m0, s0);
    asm volatile("s_waitcnt lgkmcnt(0)" ::: "memory");
    __builtin_amdgcn_s_barrier();
    __builtin_amdgcn_sched_barrier(0);
    stageV(0);

    half_pass(12, pku1, m1, s1);
    asm volatile("s_waitcnt lgkmcnt(0)" ::: "memory");
    __builtin_amdgcn_s_barrier();
    __builtin_amdgcn_sched_barrier(0);
    stageV(1);

    float m = fmaxf(m0, m1);
    float r0 = __expf(m0 - m), r1 = __expf(m1 - m);
    float inv = 1.0f / (s0 * r0 + s1 * r1);
    float w0 = r0 * inv, w1 = r1 * inv;
    #pragma unroll
    for (int q = 0; q < 12; ++q) {
        #pragma unroll
        for (int u = 0; u < 2; ++u) {
            pku0[q][u] = cvtpk(ubits_lo(pku0[q][u]) * w0, ubits_hi(pku0[q][u]) * w0);
            pku1[q][u] = cvtpk(ubits_lo(pku1[q][u]) * w1, ubits_hi(pku1[q][u]) * w1);
        }
    }

    asm volatile("s_waitcnt vmcnt(0)" ::: "memory");
    __builtin_amdgcn_s_barrier();
    __builtin_amdgcn_sched_barrier(0);

    int lA = ((g & 1) << 5) + lr;
    int lB = lA + 16;
    bool hi_ = (g & 2) != 0;
    long awrow = (bh * NS + srow0 + tl) * 257;
    f32x4 o[4];
    #pragma unroll
    for (int nt = 0; nt < 4; ++nt) o[nt] = (f32x4){0.f, 0.f, 0.f, 0.f};

    #pragma unroll
    for (int kt = 0; kt < 12; ++kt) {
        const unsigned* pa = (kt < 6) ? pku0[2 * kt]     : pku1[2 * kt - 12];
        const unsigned* pb = (kt < 6) ? pku0[2 * kt + 1] : pku1[2 * kt - 11];
        int a0 = __shfl((int)pa[0], lA, 64);
        int a1 = __shfl((int)pa[1], lA, 64);
        int a2 = __shfl((int)pa[0], lB, 64);
        int a3 = __shfl((int)pa[1], lB, 64);
        int b0 = __shfl((int)pb[0], lA, 64);
        int b1 = __shfl((int)pb[1], lA, 64);
        int b2 = __shfl((int)pb[0], lB, 64);
        int b3 = __shfl((int)pb[1], lB, 64);
        i32x4 wi;
        wi[0] = hi_ ? b0 : a0;
        wi[1] = hi_ ? b1 : a1;
        wi[2] = hi_ ? b2 : a2;
        wi[3] = hi_ ? b3 : a3;
        bf16x8 af = *(bf16x8*)&wi;

        {
            float pv_[8];
            #pragma unroll
            for (int p = 0; p < 4; ++p) {
                unsigned u = (unsigned)wi[p];
                pv_[2 * p]     = ubits_lo(u);
                pv_[2 * p + 1] = ubits_hi(u);
            }
            int c0 = kt * 32 + (g << 3) - tl;
            if (c0 >= 0 && c0 <= 2 * NW - 7) {
                f32x4 v0 = {pv_[0], pv_[1], pv_[2], pv_[3]};
                f32x4 v1 = {pv_[4], pv_[5], pv_[6], pv_[7]};
                *(f32x4*)&attw[awrow + c0] = v0;
                *(f32x4*)&attw[awrow + c0 + 4] = v1;
            } else {
                #pragma unroll
                for (int e = 0; e < 8; ++e) {
                    int c = c0 + e;
                    if (c >= 0 && c <= 2 * NW)
                        attw[awrow + c] = pv_[e];
                }
            }
        }

        #pragma unroll
        for (int nt = 0; nt < 4; ++nt) {
            int c = kt * 4 + g;
            int phys = ((c & ~7) | ((c & 7) ^ (lr & 7))) << 3;
            bf16x8 bv = *(const bf16x8*)&kvs[(nt * 16 + lr) * 384 + phys];
            o[nt] = __builtin_amdgcn_mfma_f32_16x16x32_bf16(af, bv, o[nt], 0, 0, 0);
        }
    }

    #pragma unroll
    for (int nt = 0; nt < 4; ++nt) {
        int d = nt * 16 + lr;
        int dcol = h * NHD + d;
        #pragma unroll
        for (int i = 0; i < 4; ++i) {
            int t = t0 + (g << 2) + i;
            long row = (long)b * NS + srow0 + t;
            float v = o[nt][i] + src[row * ND + dcol];
            xb[row * ND + dcol] = f2bf(v);
        }
    }
}

// ---------------- layernorm (in-place on y) ----------------
__global__ __launch_bounds__(256) void ln_kernel(float* __restrict__ y,
                                                 const float* __restrict__ g2,
                                                 const float* __restrict__ beta2) {
    int row = blockIdx.x;
    long base = (long)row * ND;
    int tid = threadIdx.x;
    float v[3];
    float s = 0.f, ss = 0.f;
    #pragma unroll
    for (int i = 0; i < 3; ++i) {
        v[i] = y[base + i * 256 + tid];
        s += v[i];
        ss += v[i] * v[i];
    }
    #pragma unroll
    for (int m = 1; m < 64; m <<= 1) {
        s += __shfl_xor(s, m, 64);
        ss += __shfl_xor(ss, m, 64);
    }
    __shared__ float red[8];
    int wid = tid >> 6, lane = tid & 63;
    if (lane == 0) { red[wid] = s; red[wid + 4] = ss; }
    __syncthreads();
    s = red[0] + red[1] + red[2] + red[3];
    ss = red[4] + red[5] + red[6] + red[7];
    float mu = s * (1.0f / ND);
    float var = ss * (1.0f / ND) - mu * mu;
    float rstd = rsqrtf(var + 1e-6f);
    #pragma unroll
    for (int i = 0; i < 3; ++i) {
        int c = i * 256 + tid;
        y[base + c] = g2[c] * (v[i] - mu) * rstd + beta2[c];
    }
}

extern "C" void kernel_launch(void* const* d_in, const int* in_sizes, int n_in,
                              void* d_out, int out_size, void* d_ws, size_t ws_size,
                              hipStream_t stream) {
    const float* src  = (const float*)d_in[0];
    const float* Wq   = (const float*)d_in[1];
    const float* bq   = (const float*)d_in[2];
    const float* Wk   = (const float*)d_in[3];
    const float* bk   = (const float*)d_in[4];
    const float* Wv   = (const float*)d_in[5];
    const float* bv   = (const float*)d_in[6];
    const float* W1   = (const float*)d_in[7];
    const float* b1   = (const float*)d_in[8];
    const float* W2   = (const float*)d_in[9];
    const float* b2   = (const float*)d_in[10];
    const float* g2   = (const float*)d_in[11];
    const float* bt2  = (const float*)d_in[12];

    float* out  = (float*)d_out;                       // y, then LN result in-place
    float* attw = out + (long)NB * NS * ND;

    char* ws = (char*)d_ws;
    const size_t SZ_XF  = (size_t)NB * NS * ND * 4;
    const size_t SZ_XB  = (size_t)NB * NS * ND * 2;
    const size_t SZ_W1T = (size_t)ND * NDFF * 2;
    const size_t SZ_W2T = (size_t)NDFF * ND * 2;
    const size_t SZ_QKV = (size_t)NB * NS * ND * 2;
    const size_t SZ_WT  = (size_t)ND * ND * 2;

    short* x_bf  = (short*)(ws + SZ_XF);
    short* W1T   = (short*)(ws + SZ_XF + SZ_XB);
    short* W2T   = (short*)(ws + SZ_XF + SZ_XB + SZ_W1T);
    char*  regA  = ws + SZ_XF + SZ_XB + SZ_W1T + SZ_W2T;
    short* srcb  = (short*)regA;
    short* WqT   = (short*)(regA + SZ_QKV);            // [2304][768] Wqkv^T contiguous
    short* qb    = (short*)(regA + SZ_QKV + 3 * SZ_WT);
    short* kb_   = (short*)(regA + 2 * SZ_QKV + 3 * SZ_WT);
    short* vb_   = (short*)(regA + 3 * SZ_QKV + 3 * SZ_WT);
    short* WkT   = WqT + (size_t)768 * ND;
    short* WvT   = WqT + (size_t)1536 * ND;
    short* hbuf  = (short*)regA;   // aliases srcb..vb_ (dead after attention)

    const int M = NB * NS;   // 8192

    // casts / transposes
    cast_bf16<<<(M * ND / 4 + 255) / 256, 256, 0, stream>>>(src, srcb, M * ND / 4);
    transpose_cast<<<dim3(ND / 32, ND / 32), 256, 0, stream>>>(Wq, WqT, ND, ND);
    transpose_cast<<<dim3(ND / 32, ND / 32), 256, 0, stream>>>(Wk, WkT, ND, ND);
    transpose_cast<<<dim3(ND / 32, ND / 32), 256, 0, stream>>>(Wv, WvT, ND, ND);
    transpose_cast<<<dim3(NDFF / 32, ND / 32), 256, 0, stream>>>(W1, W1T, ND, NDFF);
    transpose_cast<<<dim3(ND / 32, NDFF / 32), 256, 0, stream>>>(W2, W2T, NDFF, ND);

    (void)hipFuncSetAttribute(reinterpret_cast<const void*>(gemm8p<4>),
                              hipFuncAttributeMaxDynamicSharedMemorySize, 131072);
    (void)hipFuncSetAttribute(reinterpret_cast<const void*>(gemm8p<2>),
                              hipFuncAttributeMaxDynamicSharedMemorySize, 131072);

    // fused QKV projection: 256^2 8-phase, grid 9*32 = 288 (div by 8)
    gemm8p<4><<<(2304 / 256) * (M / 256), 512, 131072, stream>>>(
        srcb, WqT, bq, bk, bv, qb, M, 2304, ND, 2304 / 256);

    // band attention (static 48KB LDS)
    attn_kernel<<<NB * NH * NCH, 512, 0, stream>>>(qb, kb_, vb_, src, attw, x_bf);

    // FFN1: 256^2 8-phase, grid 12*32 = 384 (div by 8)
    gemm8p<2><<<(NDFF / 256) * (M / 256), 512, 131072, stream>>>(
        x_bf, W1T, b1, b1, b1, hbuf, M, NDFF, ND, NDFF / 256);
    // FFN2: verified 128^2 dbuf (N=768 -> only 96 blocks at 256^2), grid 6*64=384
    gemmdb<3><<<(ND / 128) * (M / 128), 256, 0, stream>>>(
        hbuf, W2T, b2, out, x_bf, M, ND, NDFF, ND / 128);

    // LayerNorm in-place
    ln_kernel<<<M, 256, 0, stream>>>(out, g2, bt2);
}

// Round 10
// 228.603 us; speedup vs baseline: 1.0604x; 1.0604x over previous
//
#include <hip/hip_runtime.h>
#include <hip/hip_bf16.h>
#include <stdint.h>

#define NB 2
#define NS 4096
#define ND 768
#define NH 12
#define NW 128
#define NDFF 3072
#define NHD 64
#define NCH 32   // NS/NW

typedef __attribute__((ext_vector_type(8))) short bf16x8;
typedef __attribute__((ext_vector_type(4))) short s16x4;
typedef __attribute__((ext_vector_type(4))) float f32x4;
typedef __attribute__((ext_vector_type(4))) int i32x4;

__device__ __forceinline__ float bf2f(short u) {
    union { unsigned int i; float f; } c;
    c.i = ((unsigned int)(unsigned short)u) << 16;
    return c.f;
}
__device__ __forceinline__ short f2bf(float f) {
    union { float f; unsigned int i; } c;
    c.f = f;
    unsigned int x = c.i;
    return (short)((x + 0x7fffu + ((x >> 16) & 1u)) >> 16);
}
__device__ __forceinline__ unsigned int cvtpk(float lo, float hi) {
    unsigned int r;
    asm("v_cvt_pk_bf16_f32 %0, %1, %2" : "=v"(r) : "v"(lo), "v"(hi));
    return r;
}
__device__ __forceinline__ float ubits_lo(unsigned u) {
    union { unsigned i; float f; } c; c.i = u << 16; return c.f;
}
__device__ __forceinline__ float ubits_hi(unsigned u) {
    union { unsigned i; float f; } c; c.i = u & 0xffff0000u; return c.f;
}

__device__ __forceinline__ void gl16(const void* g, const void* l) {
    __builtin_amdgcn_global_load_lds(
        (const __attribute__((address_space(1))) void*)g,
        (__attribute__((address_space(3))) void*)l, 16, 0, 0);
}

// ---------------- cast f32 -> bf16 (vectorized) ----------------
__global__ __launch_bounds__(256) void cast_bf16(const float* __restrict__ in,
                                                 short* __restrict__ out, int n4) {
    int i = blockIdx.x * 256 + threadIdx.x;
    if (i < n4) {
        f32x4 v = ((const f32x4*)in)[i];
        s16x4 o;
        o[0] = f2bf(v[0]); o[1] = f2bf(v[1]); o[2] = f2bf(v[2]); o[3] = f2bf(v[3]);
        ((s16x4*)out)[i] = o;
    }
}

// ---------------- transpose + cast: in[K][N] f32 -> out[N][K] bf16 ----------------
__global__ __launch_bounds__(256) void transpose_cast(const float* __restrict__ in,
                                                      short* __restrict__ out,
                                                      int K, int N) {
    __shared__ float tile[32][33];
    int kb = blockIdx.y * 32, nb = blockIdx.x * 32;
    int tx = threadIdx.x & 31, ty = threadIdx.x >> 5;   // ty 0..7
    #pragma unroll
    for (int r = ty; r < 32; r += 8)
        tile[r][tx] = in[(long)(kb + r) * N + nb + tx];
    __syncthreads();
    #pragma unroll
    for (int r = ty; r < 32; r += 8)
        out[(long)(nb + r) * K + kb + tx] = f2bf(tile[tx][r]);
}

// ---- fused 3-way transpose (Wq|Wk|Wv, each 768x768): grid.z picks source ----
__global__ __launch_bounds__(256) void transpose_cast3(const float* __restrict__ w0,
                                                       const float* __restrict__ w1,
                                                       const float* __restrict__ w2,
                                                       short* __restrict__ out) {
    __shared__ float tile[32][33];
    const float* in = (blockIdx.z == 0) ? w0 : (blockIdx.z == 1) ? w1 : w2;
    short* o = out + (size_t)blockIdx.z * ND * ND;
    int kb = blockIdx.y * 32, nb = blockIdx.x * 32;
    int tx = threadIdx.x & 31, ty = threadIdx.x >> 5;
    #pragma unroll
    for (int r = ty; r < 32; r += 8)
        tile[r][tx] = in[(long)(kb + r) * ND + nb + tx];
    __syncthreads();
    #pragma unroll
    for (int r = ty; r < 32; r += 8)
        o[(long)(nb + r) * ND + kb + tx] = f2bf(tile[tx][r]);
}

// ------------- 128x128 double-buffered GEMM (verified R4-R8 structure) -------------
// MODE 4: fused QKV epilogue (q scaled+BHSD, k BHSD, v BHDS)
// MODE 2: relu(acc+bias) -> bf16 [M][NDFF]
// MODE 3: acc+bias+bf16 residual -> f32 [M][ND]
template<int MODE>
__global__ __launch_bounds__(256, 2) void gemmdb(
    const short* __restrict__ A,
    const short* __restrict__ Bt,
    const float* __restrict__ b0,
    const float* __restrict__ b1,
    const float* __restrict__ b2,
    void* __restrict__ outp,
    const short* __restrict__ xres,
    int M, int N, int K, int gx)
{
    __shared__ short lds[2][256 * 64];   // per buf: A[128][64] | B[128][64]
    const int KT = K >> 6;

    int cpx = gridDim.x >> 3;
    int bid = blockIdx.x;
    int tile = (bid & 7) * cpx + (bid >> 3);
    int n0 = (tile % gx) * 128;
    int m0 = (tile / gx) * 128;

    int tid = threadIdx.x;
    int wid = tid >> 6, lane = tid & 63;
    int wr = wid >> 1, wc = wid & 1;          // 2x2 waves, wave tile 64x64
    int g = lane >> 4, lr = lane & 15;

    int rl = lane >> 3, sl = lane & 7;
    int soff = (sl ^ rl) << 3;                 // k-element offset (swizzled)
    const short* gA[4];
    const short* gB[4];
    #pragma unroll
    for (int c = 0; c < 4; ++c) {
        int row = c * 32 + wid * 8 + rl;
        gA[c] = A + (long)(m0 + row) * K + soff;
        gB[c] = Bt + (long)(n0 + row) * K + soff;
    }

    f32x4 acc[4][4];
    #pragma unroll
    for (int a = 0; a < 4; ++a)
        #pragma unroll
        for (int c = 0; c < 4; ++c)
            acc[a][c] = (f32x4){0.f, 0.f, 0.f, 0.f};

    auto stage = [&](int t, int buf) {
        long ko = (long)t << 6;
        #pragma unroll
        for (int c = 0; c < 4; ++c) {
            int lbase = (c * 32 + wid * 8) * 64;
            gl16(gA[c] + ko, &lds[buf][lbase]);
            gl16(gB[c] + ko, &lds[buf][128 * 64 + lbase]);
        }
    };

    stage(0, 0);
    asm volatile("s_waitcnt vmcnt(0)" ::: "memory");
    __builtin_amdgcn_s_barrier();

    int buf = 0;
    for (int t = 0; t < KT; ++t) {
        if (t + 1 < KT) stage(t + 1, buf ^ 1);
        const short* bufA = lds[buf];
        const short* bufB = lds[buf] + 128 * 64;
        bf16x8 af[2][4], bfr[2][4];
        #pragma unroll
        for (int kk = 0; kk < 2; ++kk) {
            int ph = (((kk << 2) + g) ^ (lr & 7)) << 3;   // swizzled k-slot (elems)
            #pragma unroll
            for (int mt = 0; mt < 4; ++mt)
                af[kk][mt] = *(const bf16x8*)&bufA[(wr * 64 + mt * 16 + lr) * 64 + ph];
            #pragma unroll
            for (int nt = 0; nt < 4; ++nt)
                bfr[kk][nt] = *(const bf16x8*)&bufB[(wc * 64 + nt * 16 + lr) * 64 + ph];
        }
        #pragma unroll
        for (int kk = 0; kk < 2; ++kk)
            #pragma unroll
            for (int mt = 0; mt < 4; ++mt)
                #pragma unroll
                for (int nt = 0; nt < 4; ++nt)
                    acc[mt][nt] = __builtin_amdgcn_mfma_f32_16x16x32_bf16(
                        af[kk][mt], bfr[kk][nt], acc[mt][nt], 0, 0, 0);
        asm volatile("s_waitcnt vmcnt(0)" ::: "memory");
        __builtin_amdgcn_s_barrier();
        buf ^= 1;
    }

    // ---- epilogue
    int mr0 = m0 + wr * 64;
    int nc0 = n0 + wc * 64;
    if (MODE == 4) {
        int proj = n0 / 768;   // 0=q,1=k,2=v
        const float* bp = (proj == 0) ? b0 : (proj == 1) ? b1 : b2;
        float scl = (proj == 0) ? 0.125f : 1.0f;
        short* obase = (short*)outp + (long)proj * ((long)NB * NS * ND);
        #pragma unroll
        for (int mt = 0; mt < 4; ++mt) {
            #pragma unroll
            for (int nt = 0; nt < 4; ++nt) {
                int c = nc0 + nt * 16 + lr - proj * 768;
                int hh = c >> 6, hd = c & 63;
                float bv = bp[c];
                if (proj == 2) {
                    int m = mr0 + mt * 16 + (g << 2);
                    int bbi = m >> 12, s = m & (NS - 1);
                    s16x4 ov;
                    ov[0] = f2bf(acc[mt][nt][0] + bv);
                    ov[1] = f2bf(acc[mt][nt][1] + bv);
                    ov[2] = f2bf(acc[mt][nt][2] + bv);
                    ov[3] = f2bf(acc[mt][nt][3] + bv);
                    *(s16x4*)&obase[((long)(bbi * NH + hh) * NHD + hd) * NS + s] = ov;
                } else {
                    #pragma unroll
                    for (int i = 0; i < 4; ++i) {
                        int m = mr0 + mt * 16 + (g << 2) + i;
                        int bbi = m >> 12, s = m & (NS - 1);
                        obase[((long)(bbi * NH + hh) * NS + s) * NHD + hd] =
                            f2bf((acc[mt][nt][i] + bv) * scl);
                    }
                }
            }
        }
    } else {
        #pragma unroll
        for (int mt = 0; mt < 4; ++mt) {
            #pragma unroll
            for (int nt = 0; nt < 4; ++nt) {
                int col = nc0 + nt * 16 + lr;
                float bv = b0[col];
                #pragma unroll
                for (int i = 0; i < 4; ++i) {
                    int m = mr0 + mt * 16 + (g << 2) + i;
                    float v = acc[mt][nt][i];
                    if (MODE == 2) {
                        v = fmaxf(v + bv, 0.f);
                        ((short*)outp)[(long)m * NDFF + col] = f2bf(v);
                    } else {
                        v = v + bv + bf2f(xres[(long)m * ND + col]);
                        ((float*)outp)[(long)m * ND + col] = v;
                    }
                }
            }
        }
    }
}

// ------- band attention (verified R8: swapped-QK, 2-half online softmax, 48KB LDS) -------
__global__ __launch_bounds__(512, 2) void attn_kernel(
    const short* __restrict__ qg,   // (B,H,S,HD) bf16, pre-scaled
    const short* __restrict__ kg,   // (B,H,S,HD) bf16
    const short* __restrict__ vtg,  // (B,H,HD,S) bf16
    const float* __restrict__ src,  // (B,S,D) f32
    float* __restrict__ attw,       // (B,H,S,257) f32
    short* __restrict__ xb)         // (B,S,D) bf16
{
    __shared__ short kvs[384 * 64];   // 48KB: K [384][64] -> later V [64][384]

    int blk = blockIdx.x;
    int ch = blk & 31;
    int tmp = blk >> 5;
    int h = tmp % NH;
    int b = tmp / NH;
    int tid = threadIdx.x;
    int wid = tid >> 6;
    int lane = tid & 63;
    int g = lane >> 4, lr = lane & 15;
    long bh = (long)(b * NH + h);
    long kbase = bh * NS * NHD;
    int srow0 = ch * NW;
    int t0 = wid << 4;
    int tl = t0 + lr;                 // this lane's q-row (local)

    {
        int rsub = lane >> 3;
        int pc = lane & 7;
        int lc = pc ^ rsub;
        #pragma unroll
        for (int i = 0; i < 6; ++i) {
            int inst = wid * 6 + i;
            int j = inst * 8 + rsub;
            int s = srow0 - NW + j;
            s = s < 0 ? 0 : (s >= NS ? NS - 1 : s);
            gl16(&kg[kbase + (long)s * NHD + lc * 8], &kvs[inst * 512 + lane * 8]);
        }
    }
    bf16x8 aq[2];
    #pragma unroll
    for (int kk = 0; kk < 2; ++kk)
        aq[kk] = *(const bf16x8*)&qg[kbase + (long)(srow0 + tl) * NHD + (kk << 5) + (g << 3)];

    asm volatile("s_waitcnt vmcnt(0)" ::: "memory");
    __builtin_amdgcn_s_barrier();
    __builtin_amdgcn_sched_barrier(0);

    unsigned pku0[12][2], pku1[12][2];
    float m0, s0, m1, s1;
    auto half_pass = [&](int jtb, unsigned (&pk)[12][2], float& mh, float& sh) {
        f32x4 sc[12];
        #pragma unroll
        for (int q = 0; q < 12; ++q) {
            int jt = jtb + q;
            f32x4 a = (f32x4){0.f, 0.f, 0.f, 0.f};
            #pragma unroll
            for (int kk = 0; kk < 2; ++kk) {
                int phys = (((kk << 2) + g) ^ (lr & 7)) << 3;
                bf16x8 bk = *(const bf16x8*)&kvs[(jt * 16 + lr) * 64 + phys];
                a = __builtin_amdgcn_mfma_f32_16x16x32_bf16(bk, aq[kk], a, 0, 0, 0);
            }
            sc[q] = a;
        }
        float mx = -3.0e30f;
        #pragma unroll
        for (int q = 0; q < 12; ++q) {
            int j0 = (jtb + q) * 16 + (g << 2);
            #pragma unroll
            for (int i = 0; i < 4; ++i) {
                int j = j0 + i;
                int sp = srow0 - NW + j;
                bool ok = (sp >= 0) && (sp < NS) && (j >= tl) && (j <= tl + 2 * NW);
                float v = ok ? sc[q][i] : -3.0e30f;
                sc[q][i] = v;
                mx = fmaxf(mx, v);
            }
        }
        mx = fmaxf(mx, __shfl_xor(mx, 16, 64));
        mx = fmaxf(mx, __shfl_xor(mx, 32, 64));
        float sm = 0.f;
        #pragma unroll
        for (int q = 0; q < 12; ++q) {
            #pragma unroll
            for (int i = 0; i < 4; ++i) {
                float v = sc[q][i];
                float p = (v > -1.0e30f) ? __expf(v - mx) : 0.0f;
                sc[q][i] = p;
                sm += p;
            }
            pk[q][0] = cvtpk(sc[q][0], sc[q][1]);
            pk[q][1] = cvtpk(sc[q][2], sc[q][3]);
        }
        sm += __shfl_xor(sm, 16, 64);
        sm += __shfl_xor(sm, 32, 64);
        mh = mx; sh = sm;
    };

    auto stageV = [&](int hf) {
        #pragma unroll
        for (int i = 0; i < 3; ++i) {
            int v = wid * 3 + i;
            int fc = hf * 1536 + v * 64 + lane;
            int hd = fc / 48;
            int pc = fc % 48;
            int lc = (pc & ~7) | ((pc & 7) ^ (hd & 7));
            int scol = srow0 - NW + lc * 8;
            scol = scol < 0 ? 0 : (scol > NS - 8 ? NS - 8 : scol);
            gl16(&vtg[(bh * NHD + hd) * NS + scol],
                 &kvs[hf * 12288 + v * 512 + lane * 8]);
        }
    };

    half_pass(0, pku0, m0, s0);
    asm volatile("s_waitcnt lgkmcnt(0)" ::: "memory");
    __builtin_amdgcn_s_barrier();
    __builtin_amdgcn_sched_barrier(0);
    stageV(0);

    half_pass(12, pku1, m1, s1);
    asm volatile("s_waitcnt lgkmcnt(0)" ::: "memory");
    __builtin_amdgcn_s_barrier();
    __builtin_amdgcn_sched_barrier(0);
    stageV(1);

    float m = fmaxf(m0, m1);
    float r0 = __expf(m0 - m), r1 = __expf(m1 - m);
    float inv = 1.0f / (s0 * r0 + s1 * r1);
    float w0 = r0 * inv, w1 = r1 * inv;
    #pragma unroll
    for (int q = 0; q < 12; ++q) {
        #pragma unroll
        for (int u = 0; u < 2; ++u) {
            pku0[q][u] = cvtpk(ubits_lo(pku0[q][u]) * w0, ubits_hi(pku0[q][u]) * w0);
            pku1[q][u] = cvtpk(ubits_lo(pku1[q][u]) * w1, ubits_hi(pku1[q][u]) * w1);
        }
    }

    asm volatile("s_waitcnt vmcnt(0)" ::: "memory");
    __builtin_amdgcn_s_barrier();
    __builtin_amdgcn_sched_barrier(0);

    int lA = ((g & 1) << 5) + lr;
    int lB = lA + 16;
    bool hi_ = (g & 2) != 0;
    long awrow = (bh * NS + srow0 + tl) * 257;
    f32x4 o[4];
    #pragma unroll
    for (int nt = 0; nt < 4; ++nt) o[nt] = (f32x4){0.f, 0.f, 0.f, 0.f};

    #pragma unroll
    for (int kt = 0; kt < 12; ++kt) {
        const unsigned* pa = (kt < 6) ? pku0[2 * kt]     : pku1[2 * kt - 12];
        const unsigned* pb = (kt < 6) ? pku0[2 * kt + 1] : pku1[2 * kt - 11];
        int a0 = __shfl((int)pa[0], lA, 64);
        int a1 = __shfl((int)pa[1], lA, 64);
        int a2 = __shfl((int)pa[0], lB, 64);
        int a3 = __shfl((int)pa[1], lB, 64);
        int b0 = __shfl((int)pb[0], lA, 64);
        int b1 = __shfl((int)pb[1], lA, 64);
        int b2 = __shfl((int)pb[0], lB, 64);
        int b3 = __shfl((int)pb[1], lB, 64);
        i32x4 wi;
        wi[0] = hi_ ? b0 : a0;
        wi[1] = hi_ ? b1 : a1;
        wi[2] = hi_ ? b2 : a2;
        wi[3] = hi_ ? b3 : a3;
        bf16x8 af = *(bf16x8*)&wi;

        {
            float pv_[8];
            #pragma unroll
            for (int p = 0; p < 4; ++p) {
                unsigned u = (unsigned)wi[p];
                pv_[2 * p]     = ubits_lo(u);
                pv_[2 * p + 1] = ubits_hi(u);
            }
            int c0 = kt * 32 + (g << 3) - tl;
            if (c0 >= 0 && c0 <= 2 * NW - 7) {
                f32x4 v0 = {pv_[0], pv_[1], pv_[2], pv_[3]};
                f32x4 v1 = {pv_[4], pv_[5], pv_[6], pv_[7]};
                *(f32x4*)&attw[awrow + c0] = v0;
                *(f32x4*)&attw[awrow + c0 + 4] = v1;
            } else {
                #pragma unroll
                for (int e = 0; e < 8; ++e) {
                    int c = c0 + e;
                    if (c >= 0 && c <= 2 * NW)
                        attw[awrow + c] = pv_[e];
                }
            }
        }

        #pragma unroll
        for (int nt = 0; nt < 4; ++nt) {
            int c = kt * 4 + g;
            int phys = ((c & ~7) | ((c & 7) ^ (lr & 7))) << 3;
            bf16x8 bv = *(const bf16x8*)&kvs[(nt * 16 + lr) * 384 + phys];
            o[nt] = __builtin_amdgcn_mfma_f32_16x16x32_bf16(af, bv, o[nt], 0, 0, 0);
        }
    }

    #pragma unroll
    for (int nt = 0; nt < 4; ++nt) {
        int d = nt * 16 + lr;
        int dcol = h * NHD + d;
        #pragma unroll
        for (int i = 0; i < 4; ++i) {
            int t = t0 + (g << 2) + i;
            long row = (long)b * NS + srow0 + t;
            float v = o[nt][i] + src[row * ND + dcol];
            xb[row * ND + dcol] = f2bf(v);
        }
    }
}

// ---------------- layernorm (in-place on y) ----------------
__global__ __launch_bounds__(256) void ln_kernel(float* __restrict__ y,
                                                 const float* __restrict__ g2,
                                                 const float* __restrict__ beta2) {
    int row = blockIdx.x;
    long base = (long)row * ND;
    int tid = threadIdx.x;
    float v[3];
    float s = 0.f, ss = 0.f;
    #pragma unroll
    for (int i = 0; i < 3; ++i) {
        v[i] = y[base + i * 256 + tid];
        s += v[i];
        ss += v[i] * v[i];
    }
    #pragma unroll
    for (int m = 1; m < 64; m <<= 1) {
        s += __shfl_xor(s, m, 64);
        ss += __shfl_xor(ss, m, 64);
    }
    __shared__ float red[8];
    int wid = tid >> 6, lane = tid & 63;
    if (lane == 0) { red[wid] = s; red[wid + 4] = ss; }
    __syncthreads();
    s = red[0] + red[1] + red[2] + red[3];
    ss = red[4] + red[5] + red[6] + red[7];
    float mu = s * (1.0f / ND);
    float var = ss * (1.0f / ND) - mu * mu;
    float rstd = rsqrtf(var + 1e-6f);
    #pragma unroll
    for (int i = 0; i < 3; ++i) {
        int c = i * 256 + tid;
        y[base + c] = g2[c] * (v[i] - mu) * rstd + beta2[c];
    }
}

extern "C" void kernel_launch(void* const* d_in, const int* in_sizes, int n_in,
                              void* d_out, int out_size, void* d_ws, size_t ws_size,
                              hipStream_t stream) {
    const float* src  = (const float*)d_in[0];
    const float* Wq   = (const float*)d_in[1];
    const float* bq   = (const float*)d_in[2];
    const float* Wk   = (const float*)d_in[3];
    const float* bk   = (const float*)d_in[4];
    const float* Wv   = (const float*)d_in[5];
    const float* bv   = (const float*)d_in[6];
    const float* W1   = (const float*)d_in[7];
    const float* b1   = (const float*)d_in[8];
    const float* W2   = (const float*)d_in[9];
    const float* b2   = (const float*)d_in[10];
    const float* g2   = (const float*)d_in[11];
    const float* bt2  = (const float*)d_in[12];

    float* out  = (float*)d_out;                       // y, then LN result in-place
    float* attw = out + (long)NB * NS * ND;

    char* ws = (char*)d_ws;
    const size_t SZ_XF  = (size_t)NB * NS * ND * 4;
    const size_t SZ_XB  = (size_t)NB * NS * ND * 2;
    const size_t SZ_W1T = (size_t)ND * NDFF * 2;
    const size_t SZ_W2T = (size_t)NDFF * ND * 2;
    const size_t SZ_QKV = (size_t)NB * NS * ND * 2;
    const size_t SZ_WT  = (size_t)ND * ND * 2;

    short* x_bf  = (short*)(ws + SZ_XF);
    short* W1T   = (short*)(ws + SZ_XF + SZ_XB);
    short* W2T   = (short*)(ws + SZ_XF + SZ_XB + SZ_W1T);
    char*  regA  = ws + SZ_XF + SZ_XB + SZ_W1T + SZ_W2T;
    short* srcb  = (short*)regA;
    short* WqT   = (short*)(regA + SZ_QKV);            // [2304][768] Wqkv^T contiguous
    short* qb    = (short*)(regA + SZ_QKV + 3 * SZ_WT);
    short* kb_   = (short*)(regA + 2 * SZ_QKV + 3 * SZ_WT);
    short* vb_   = (short*)(regA + 3 * SZ_QKV + 3 * SZ_WT);
    short* hbuf  = (short*)regA;   // aliases srcb..vb_ (dead after attention)

    const int M = NB * NS;   // 8192

    // casts / transposes (QKV weight transposes fused into one launch)
    cast_bf16<<<(M * ND / 4 + 255) / 256, 256, 0, stream>>>(src, srcb, M * ND / 4);
    transpose_cast3<<<dim3(ND / 32, ND / 32, 3), 256, 0, stream>>>(Wq, Wk, Wv, WqT);
    transpose_cast<<<dim3(NDFF / 32, ND / 32), 256, 0, stream>>>(W1, W1T, ND, NDFF);
    transpose_cast<<<dim3(ND / 32, NDFF / 32), 256, 0, stream>>>(W2, W2T, NDFF, ND);

    // fused QKV projection (N = 2304 = q|k|v), grid 18*64 = 1152 (div by 8)
    gemmdb<4><<<(2304 / 128) * (M / 128), 256, 0, stream>>>(
        srcb, WqT, bq, bk, bv, qb, nullptr, M, 2304, ND, 2304 / 128);

    // band attention (static 48KB LDS)
    attn_kernel<<<NB * NH * NCH, 512, 0, stream>>>(qb, kb_, vb_, src, attw, x_bf);

    // FFN: grids 24*64 = 1536 and 6*64 = 384 (both div by 8)
    gemmdb<2><<<(NDFF / 128) * (M / 128), 256, 0, stream>>>(
        x_bf, W1T, b1, b1, b1, hbuf, nullptr, M, NDFF, ND, NDFF / 128);
    gemmdb<3><<<(ND / 128) * (M / 128), 256, 0, stream>>>(
        hbuf, W2T, b2, b2, b2, out, x_bf, M, ND, NDFF, ND / 128);

    // LayerNorm in-place
    ln_kernel<<<M, 256, 0, stream>>>(out, g2, bt2);
}

// Round 11
// 216.905 us; speedup vs baseline: 1.1176x; 1.0539x over previous
//
#include <hip/hip_runtime.h>
#include <hip/hip_bf16.h>
#include <stdint.h>

#define NB 2
#define NS 4096
#define ND 768
#define NH 12
#define NW 128
#define NDFF 3072
#define NHD 64
#define NCH 32   // NS/NW

typedef __attribute__((ext_vector_type(8))) short bf16x8;
typedef __attribute__((ext_vector_type(4))) short s16x4;
typedef __attribute__((ext_vector_type(4))) float f32x4;
typedef __attribute__((ext_vector_type(4))) int i32x4;

__device__ __forceinline__ float bf2f(short u) {
    union { unsigned int i; float f; } c;
    c.i = ((unsigned int)(unsigned short)u) << 16;
    return c.f;
}
__device__ __forceinline__ short f2bf(float f) {
    union { float f; unsigned int i; } c;
    c.f = f;
    unsigned int x = c.i;
    return (short)((x + 0x7fffu + ((x >> 16) & 1u)) >> 16);
}
__device__ __forceinline__ unsigned int cvtpk(float lo, float hi) {
    unsigned int r;
    asm("v_cvt_pk_bf16_f32 %0, %1, %2" : "=v"(r) : "v"(lo), "v"(hi));
    return r;
}
__device__ __forceinline__ float ubits_lo(unsigned u) {
    union { unsigned i; float f; } c; c.i = u << 16; return c.f;
}
__device__ __forceinline__ float ubits_hi(unsigned u) {
    union { unsigned i; float f; } c; c.i = u & 0xffff0000u; return c.f;
}

__device__ __forceinline__ void gl16(const void* g, const void* l) {
    __builtin_amdgcn_global_load_lds(
        (const __attribute__((address_space(1))) void*)g,
        (__attribute__((address_space(3))) void*)l, 16, 0, 0);
}

// ======== fused prep: all weight transposes + src cast in ONE launch ========
// blocks 0..1727    : Wq/Wk/Wv transpose (576 tiles each) -> WqkvT [2304][768]
// blocks 1728..4031 : W1 [768][3072] -> W1T [3072][768]
// blocks 4032..6335 : W2 [3072][768] -> W2T [768][3072]
// blocks 6336..12479: src f32 -> bf16 cast (6144 blocks x 1024 elems)
__global__ __launch_bounds__(256) void prep_kernel(
    const float* __restrict__ Wq, const float* __restrict__ Wk,
    const float* __restrict__ Wv, const float* __restrict__ W1,
    const float* __restrict__ W2, const float* __restrict__ src,
    short* __restrict__ WqkvT, short* __restrict__ W1T,
    short* __restrict__ W2T,   short* __restrict__ srcb)
{
    int id = blockIdx.x;
    if (id >= 6336) {
        int i = (id - 6336) * 256 + threadIdx.x;   // < 1572864 = 8192*768/4 exactly
        f32x4 v = ((const f32x4*)src)[i];
        s16x4 o;
        o[0] = f2bf(v[0]); o[1] = f2bf(v[1]); o[2] = f2bf(v[2]); o[3] = f2bf(v[3]);
        ((s16x4*)srcb)[i] = o;
        return;
    }
    __shared__ float tile[32][33];
    const float* in; short* out; int K, N, bx, by;
    if (id < 1728) {
        int z = id / 576, t = id % 576;
        in = (z == 0) ? Wq : (z == 1) ? Wk : Wv;
        out = WqkvT + (size_t)z * ND * ND;
        K = ND; N = ND; bx = t % 24; by = t / 24;
    } else if (id < 4032) {
        int t = id - 1728;
        in = W1; out = W1T; K = ND; N = NDFF; bx = t % 96; by = t / 96;
    } else {
        int t = id - 4032;
        in = W2; out = W2T; K = NDFF; N = ND; bx = t % 24; by = t / 24;
    }
    int kb = by * 32, nb = bx * 32;
    int tx = threadIdx.x & 31, ty = threadIdx.x >> 5;
    #pragma unroll
    for (int r = ty; r < 32; r += 8)
        tile[r][tx] = in[(long)(kb + r) * N + nb + tx];
    __syncthreads();
    #pragma unroll
    for (int r = ty; r < 32; r += 8)
        out[(long)(nb + r) * K + kb + tx] = f2bf(tile[tx][r]);
}

// ------------- 128x128 double-buffered GEMM (verified R4-R10 structure) -------------
// MODE 4: fused QKV epilogue (q scaled+BHSD, k BHSD, v BHDS)
// MODE 2: relu(acc+bias) -> bf16 [M][NDFF]
// MODE 3: acc+bias+bf16 residual -> f32 [M][ND]
template<int MODE>
__global__ __launch_bounds__(256, 2) void gemmdb(
    const short* __restrict__ A,
    const short* __restrict__ Bt,
    const float* __restrict__ b0,
    const float* __restrict__ b1,
    const float* __restrict__ b2,
    void* __restrict__ outp,
    const short* __restrict__ xres,
    int M, int N, int K, int gx)
{
    __shared__ short lds[2][256 * 64];   // per buf: A[128][64] | B[128][64]
    const int KT = K >> 6;

    int cpx = gridDim.x >> 3;
    int bid = blockIdx.x;
    int tile = (bid & 7) * cpx + (bid >> 3);
    int n0 = (tile % gx) * 128;
    int m0 = (tile / gx) * 128;

    int tid = threadIdx.x;
    int wid = tid >> 6, lane = tid & 63;
    int wr = wid >> 1, wc = wid & 1;          // 2x2 waves, wave tile 64x64
    int g = lane >> 4, lr = lane & 15;

    int rl = lane >> 3, sl = lane & 7;
    int soff = (sl ^ rl) << 3;                 // k-element offset (swizzled)
    const short* gA[4];
    const short* gB[4];
    #pragma unroll
    for (int c = 0; c < 4; ++c) {
        int row = c * 32 + wid * 8 + rl;
        gA[c] = A + (long)(m0 + row) * K + soff;
        gB[c] = Bt + (long)(n0 + row) * K + soff;
    }

    f32x4 acc[4][4];
    #pragma unroll
    for (int a = 0; a < 4; ++a)
        #pragma unroll
        for (int c = 0; c < 4; ++c)
            acc[a][c] = (f32x4){0.f, 0.f, 0.f, 0.f};

    auto stage = [&](int t, int buf) {
        long ko = (long)t << 6;
        #pragma unroll
        for (int c = 0; c < 4; ++c) {
            int lbase = (c * 32 + wid * 8) * 64;
            gl16(gA[c] + ko, &lds[buf][lbase]);
            gl16(gB[c] + ko, &lds[buf][128 * 64 + lbase]);
        }
    };

    stage(0, 0);
    asm volatile("s_waitcnt vmcnt(0)" ::: "memory");
    __builtin_amdgcn_s_barrier();

    int buf = 0;
    for (int t = 0; t < KT; ++t) {
        if (t + 1 < KT) stage(t + 1, buf ^ 1);
        const short* bufA = lds[buf];
        const short* bufB = lds[buf] + 128 * 64;
        bf16x8 af[2][4], bfr[2][4];
        #pragma unroll
        for (int kk = 0; kk < 2; ++kk) {
            int ph = (((kk << 2) + g) ^ (lr & 7)) << 3;   // swizzled k-slot (elems)
            #pragma unroll
            for (int mt = 0; mt < 4; ++mt)
                af[kk][mt] = *(const bf16x8*)&bufA[(wr * 64 + mt * 16 + lr) * 64 + ph];
            #pragma unroll
            for (int nt = 0; nt < 4; ++nt)
                bfr[kk][nt] = *(const bf16x8*)&bufB[(wc * 64 + nt * 16 + lr) * 64 + ph];
        }
        #pragma unroll
        for (int kk = 0; kk < 2; ++kk)
            #pragma unroll
            for (int mt = 0; mt < 4; ++mt)
                #pragma unroll
                for (int nt = 0; nt < 4; ++nt)
                    acc[mt][nt] = __builtin_amdgcn_mfma_f32_16x16x32_bf16(
                        af[kk][mt], bfr[kk][nt], acc[mt][nt], 0, 0, 0);
        asm volatile("s_waitcnt vmcnt(0)" ::: "memory");
        __builtin_amdgcn_s_barrier();
        buf ^= 1;
    }

    // ---- epilogue
    int mr0 = m0 + wr * 64;
    int nc0 = n0 + wc * 64;
    if (MODE == 4) {
        int proj = n0 / 768;   // 0=q,1=k,2=v
        const float* bp = (proj == 0) ? b0 : (proj == 1) ? b1 : b2;
        float scl = (proj == 0) ? 0.125f : 1.0f;
        short* obase = (short*)outp + (long)proj * ((long)NB * NS * ND);
        #pragma unroll
        for (int mt = 0; mt < 4; ++mt) {
            #pragma unroll
            for (int nt = 0; nt < 4; ++nt) {
                int c = nc0 + nt * 16 + lr - proj * 768;
                int hh = c >> 6, hd = c & 63;
                float bv = bp[c];
                if (proj == 2) {
                    int m = mr0 + mt * 16 + (g << 2);
                    int bbi = m >> 12, s = m & (NS - 1);
                    s16x4 ov;
                    ov[0] = f2bf(acc[mt][nt][0] + bv);
                    ov[1] = f2bf(acc[mt][nt][1] + bv);
                    ov[2] = f2bf(acc[mt][nt][2] + bv);
                    ov[3] = f2bf(acc[mt][nt][3] + bv);
                    *(s16x4*)&obase[((long)(bbi * NH + hh) * NHD + hd) * NS + s] = ov;
                } else {
                    #pragma unroll
                    for (int i = 0; i < 4; ++i) {
                        int m = mr0 + mt * 16 + (g << 2) + i;
                        int bbi = m >> 12, s = m & (NS - 1);
                        obase[((long)(bbi * NH + hh) * NS + s) * NHD + hd] =
                            f2bf((acc[mt][nt][i] + bv) * scl);
                    }
                }
            }
        }
    } else {
        #pragma unroll
        for (int mt = 0; mt < 4; ++mt) {
            #pragma unroll
            for (int nt = 0; nt < 4; ++nt) {
                int col = nc0 + nt * 16 + lr;
                float bv = b0[col];
                #pragma unroll
                for (int i = 0; i < 4; ++i) {
                    int m = mr0 + mt * 16 + (g << 2) + i;
                    float v = acc[mt][nt][i];
                    if (MODE == 2) {
                        v = fmaxf(v + bv, 0.f);
                        ((short*)outp)[(long)m * NDFF + col] = f2bf(v);
                    } else {
                        v = v + bv + bf2f(xres[(long)m * ND + col]);
                        ((float*)outp)[(long)m * ND + col] = v;
                    }
                }
            }
        }
    }
}

// ------- band attention (verified R8 body + T1 XCD-chunked block swizzle) -------
__global__ __launch_bounds__(512, 2) void attn_kernel(
    const short* __restrict__ qg,   // (B,H,S,HD) bf16, pre-scaled
    const short* __restrict__ kg,   // (B,H,S,HD) bf16
    const short* __restrict__ vtg,  // (B,H,HD,S) bf16
    const float* __restrict__ src,  // (B,S,D) f32
    float* __restrict__ attw,       // (B,H,S,257) f32
    short* __restrict__ xb)         // (B,S,D) bf16
{
    __shared__ short kvs[384 * 64];   // 48KB: K [384][64] -> later V [64][384]

    // XCD swizzle: 768 blocks = 8 x 96; neighbors (same b,h; adjacent ch) share
    // 256 of 384 K/V halo rows -> keep them on the same XCD's L2.
    int bid = blockIdx.x;
    int blk = (bid & 7) * (NB * NH * NCH / 8) + (bid >> 3);
    int ch = blk & 31;
    int tmp = blk >> 5;
    int h = tmp % NH;
    int b = tmp / NH;
    int tid = threadIdx.x;
    int wid = tid >> 6;
    int lane = tid & 63;
    int g = lane >> 4, lr = lane & 15;
    long bh = (long)(b * NH + h);
    long kbase = bh * NS * NHD;
    int srow0 = ch * NW;
    int t0 = wid << 4;
    int tl = t0 + lr;                 // this lane's q-row (local)

    {
        int rsub = lane >> 3;
        int pc = lane & 7;
        int lc = pc ^ rsub;
        #pragma unroll
        for (int i = 0; i < 6; ++i) {
            int inst = wid * 6 + i;
            int j = inst * 8 + rsub;
            int s = srow0 - NW + j;
            s = s < 0 ? 0 : (s >= NS ? NS - 1 : s);
            gl16(&kg[kbase + (long)s * NHD + lc * 8], &kvs[inst * 512 + lane * 8]);
        }
    }
    bf16x8 aq[2];
    #pragma unroll
    for (int kk = 0; kk < 2; ++kk)
        aq[kk] = *(const bf16x8*)&qg[kbase + (long)(srow0 + tl) * NHD + (kk << 5) + (g << 3)];

    asm volatile("s_waitcnt vmcnt(0)" ::: "memory");
    __builtin_amdgcn_s_barrier();
    __builtin_amdgcn_sched_barrier(0);

    unsigned pku0[12][2], pku1[12][2];
    float m0, s0, m1, s1;
    auto half_pass = [&](int jtb, unsigned (&pk)[12][2], float& mh, float& sh) {
        f32x4 sc[12];
        #pragma unroll
        for (int q = 0; q < 12; ++q) {
            int jt = jtb + q;
            f32x4 a = (f32x4){0.f, 0.f, 0.f, 0.f};
            #pragma unroll
            for (int kk = 0; kk < 2; ++kk) {
                int phys = (((kk << 2) + g) ^ (lr & 7)) << 3;
                bf16x8 bk = *(const bf16x8*)&kvs[(jt * 16 + lr) * 64 + phys];
                a = __builtin_amdgcn_mfma_f32_16x16x32_bf16(bk, aq[kk], a, 0, 0, 0);
            }
            sc[q] = a;
        }
        float mx = -3.0e30f;
        #pragma unroll
        for (int q = 0; q < 12; ++q) {
            int j0 = (jtb + q) * 16 + (g << 2);
            #pragma unroll
            for (int i = 0; i < 4; ++i) {
                int j = j0 + i;
                int sp = srow0 - NW + j;
                bool ok = (sp >= 0) && (sp < NS) && (j >= tl) && (j <= tl + 2 * NW);
                float v = ok ? sc[q][i] : -3.0e30f;
                sc[q][i] = v;
                mx = fmaxf(mx, v);
            }
        }
        mx = fmaxf(mx, __shfl_xor(mx, 16, 64));
        mx = fmaxf(mx, __shfl_xor(mx, 32, 64));
        float sm = 0.f;
        #pragma unroll
        for (int q = 0; q < 12; ++q) {
            #pragma unroll
            for (int i = 0; i < 4; ++i) {
                float v = sc[q][i];
                float p = (v > -1.0e30f) ? __expf(v - mx) : 0.0f;
                sc[q][i] = p;
                sm += p;
            }
            pk[q][0] = cvtpk(sc[q][0], sc[q][1]);
            pk[q][1] = cvtpk(sc[q][2], sc[q][3]);
        }
        sm += __shfl_xor(sm, 16, 64);
        sm += __shfl_xor(sm, 32, 64);
        mh = mx; sh = sm;
    };

    auto stageV = [&](int hf) {
        #pragma unroll
        for (int i = 0; i < 3; ++i) {
            int v = wid * 3 + i;
            int fc = hf * 1536 + v * 64 + lane;
            int hd = fc / 48;
            int pc = fc % 48;
            int lc = (pc & ~7) | ((pc & 7) ^ (hd & 7));
            int scol = srow0 - NW + lc * 8;
            scol = scol < 0 ? 0 : (scol > NS - 8 ? NS - 8 : scol);
            gl16(&vtg[(bh * NHD + hd) * NS + scol],
                 &kvs[hf * 12288 + v * 512 + lane * 8]);
        }
    };

    half_pass(0, pku0, m0, s0);
    asm volatile("s_waitcnt lgkmcnt(0)" ::: "memory");
    __builtin_amdgcn_s_barrier();
    __builtin_amdgcn_sched_barrier(0);
    stageV(0);

    half_pass(12, pku1, m1, s1);
    asm volatile("s_waitcnt lgkmcnt(0)" ::: "memory");
    __builtin_amdgcn_s_barrier();
    __builtin_amdgcn_sched_barrier(0);
    stageV(1);

    float m = fmaxf(m0, m1);
    float r0 = __expf(m0 - m), r1 = __expf(m1 - m);
    float inv = 1.0f / (s0 * r0 + s1 * r1);
    float w0 = r0 * inv, w1 = r1 * inv;
    #pragma unroll
    for (int q = 0; q < 12; ++q) {
        #pragma unroll
        for (int u = 0; u < 2; ++u) {
            pku0[q][u] = cvtpk(ubits_lo(pku0[q][u]) * w0, ubits_hi(pku0[q][u]) * w0);
            pku1[q][u] = cvtpk(ubits_lo(pku1[q][u]) * w1, ubits_hi(pku1[q][u]) * w1);
        }
    }

    asm volatile("s_waitcnt vmcnt(0)" ::: "memory");
    __builtin_amdgcn_s_barrier();
    __builtin_amdgcn_sched_barrier(0);

    int lA = ((g & 1) << 5) + lr;
    int lB = lA + 16;
    bool hi_ = (g & 2) != 0;
    long awrow = (bh * NS + srow0 + tl) * 257;
    f32x4 o[4];
    #pragma unroll
    for (int nt = 0; nt < 4; ++nt) o[nt] = (f32x4){0.f, 0.f, 0.f, 0.f};

    #pragma unroll
    for (int kt = 0; kt < 12; ++kt) {
        const unsigned* pa = (kt < 6) ? pku0[2 * kt]     : pku1[2 * kt - 12];
        const unsigned* pb = (kt < 6) ? pku0[2 * kt + 1] : pku1[2 * kt - 11];
        int a0 = __shfl((int)pa[0], lA, 64);
        int a1 = __shfl((int)pa[1], lA, 64);
        int a2 = __shfl((int)pa[0], lB, 64);
        int a3 = __shfl((int)pa[1], lB, 64);
        int b0 = __shfl((int)pb[0], lA, 64);
        int b1 = __shfl((int)pb[1], lA, 64);
        int b2 = __shfl((int)pb[0], lB, 64);
        int b3 = __shfl((int)pb[1], lB, 64);
        i32x4 wi;
        wi[0] = hi_ ? b0 : a0;
        wi[1] = hi_ ? b1 : a1;
        wi[2] = hi_ ? b2 : a2;
        wi[3] = hi_ ? b3 : a3;
        bf16x8 af = *(bf16x8*)&wi;

        {
            float pv_[8];
            #pragma unroll
            for (int p = 0; p < 4; ++p) {
                unsigned u = (unsigned)wi[p];
                pv_[2 * p]     = ubits_lo(u);
                pv_[2 * p + 1] = ubits_hi(u);
            }
            int c0 = kt * 32 + (g << 3) - tl;
            if (c0 >= 0 && c0 <= 2 * NW - 7) {
                f32x4 v0 = {pv_[0], pv_[1], pv_[2], pv_[3]};
                f32x4 v1 = {pv_[4], pv_[5], pv_[6], pv_[7]};
                *(f32x4*)&attw[awrow + c0] = v0;
                *(f32x4*)&attw[awrow + c0 + 4] = v1;
            } else {
                #pragma unroll
                for (int e = 0; e < 8; ++e) {
                    int c = c0 + e;
                    if (c >= 0 && c <= 2 * NW)
                        attw[awrow + c] = pv_[e];
                }
            }
        }

        #pragma unroll
        for (int nt = 0; nt < 4; ++nt) {
            int c = kt * 4 + g;
            int phys = ((c & ~7) | ((c & 7) ^ (lr & 7))) << 3;
            bf16x8 bv = *(const bf16x8*)&kvs[(nt * 16 + lr) * 384 + phys];
            o[nt] = __builtin_amdgcn_mfma_f32_16x16x32_bf16(af, bv, o[nt], 0, 0, 0);
        }
    }

    #pragma unroll
    for (int nt = 0; nt < 4; ++nt) {
        int d = nt * 16 + lr;
        int dcol = h * NHD + d;
        #pragma unroll
        for (int i = 0; i < 4; ++i) {
            int t = t0 + (g << 2) + i;
            long row = (long)b * NS + srow0 + t;
            float v = o[nt][i] + src[row * ND + dcol];
            xb[row * ND + dcol] = f2bf(v);
        }
    }
}

// ---------------- layernorm (in-place on y) ----------------
__global__ __launch_bounds__(256) void ln_kernel(float* __restrict__ y,
                                                 const float* __restrict__ g2,
                                                 const float* __restrict__ beta2) {
    int row = blockIdx.x;
    long base = (long)row * ND;
    int tid = threadIdx.x;
    float v[3];
    float s = 0.f, ss = 0.f;
    #pragma unroll
    for (int i = 0; i < 3; ++i) {
        v[i] = y[base + i * 256 + tid];
        s += v[i];
        ss += v[i] * v[i];
    }
    #pragma unroll
    for (int m = 1; m < 64; m <<= 1) {
        s += __shfl_xor(s, m, 64);
        ss += __shfl_xor(ss, m, 64);
    }
    __shared__ float red[8];
    int wid = tid >> 6, lane = tid & 63;
    if (lane == 0) { red[wid] = s; red[wid + 4] = ss; }
    __syncthreads();
    s = red[0] + red[1] + red[2] + red[3];
    ss = red[4] + red[5] + red[6] + red[7];
    float mu = s * (1.0f / ND);
    float var = ss * (1.0f / ND) - mu * mu;
    float rstd = rsqrtf(var + 1e-6f);
    #pragma unroll
    for (int i = 0; i < 3; ++i) {
        int c = i * 256 + tid;
        y[base + c] = g2[c] * (v[i] - mu) * rstd + beta2[c];
    }
}

extern "C" void kernel_launch(void* const* d_in, const int* in_sizes, int n_in,
                              void* d_out, int out_size, void* d_ws, size_t ws_size,
                              hipStream_t stream) {
    const float* src  = (const float*)d_in[0];
    const float* Wq   = (const float*)d_in[1];
    const float* bq   = (const float*)d_in[2];
    const float* Wk   = (const float*)d_in[3];
    const float* bk   = (const float*)d_in[4];
    const float* Wv   = (const float*)d_in[5];
    const float* bv   = (const float*)d_in[6];
    const float* W1   = (const float*)d_in[7];
    const float* b1   = (const float*)d_in[8];
    const float* W2   = (const float*)d_in[9];
    const float* b2   = (const float*)d_in[10];
    const float* g2   = (const float*)d_in[11];
    const float* bt2  = (const float*)d_in[12];

    float* out  = (float*)d_out;                       // y, then LN result in-place
    float* attw = out + (long)NB * NS * ND;

    char* ws = (char*)d_ws;
    const size_t SZ_XF  = (size_t)NB * NS * ND * 4;
    const size_t SZ_XB  = (size_t)NB * NS * ND * 2;
    const size_t SZ_W1T = (size_t)ND * NDFF * 2;
    const size_t SZ_W2T = (size_t)NDFF * ND * 2;
    const size_t SZ_QKV = (size_t)NB * NS * ND * 2;
    const size_t SZ_WT  = (size_t)ND * ND * 2;

    short* x_bf  = (short*)(ws + SZ_XF);
    short* W1T   = (short*)(ws + SZ_XF + SZ_XB);
    short* W2T   = (short*)(ws + SZ_XF + SZ_XB + SZ_W1T);
    char*  regA  = ws + SZ_XF + SZ_XB + SZ_W1T + SZ_W2T;
    short* srcb  = (short*)regA;
    short* WqT   = (short*)(regA + SZ_QKV);            // [2304][768] Wqkv^T contiguous
    short* qb    = (short*)(regA + SZ_QKV + 3 * SZ_WT);
    short* kb_   = (short*)(regA + 2 * SZ_QKV + 3 * SZ_WT);
    short* vb_   = (short*)(regA + 3 * SZ_QKV + 3 * SZ_WT);
    short* hbuf  = (short*)regA;   // aliases srcb..vb_ (dead after attention)

    const int M = NB * NS;   // 8192

    // fused prep: QKV/W1/W2 transposes + src cast, one launch (12480 blocks)
    prep_kernel<<<12480, 256, 0, stream>>>(Wq, Wk, Wv, W1, W2, src,
                                           WqT, W1T, W2T, srcb);

    // fused QKV projection (N = 2304 = q|k|v), grid 18*64 = 1152 (div by 8)
    gemmdb<4><<<(2304 / 128) * (M / 128), 256, 0, stream>>>(
        srcb, WqT, bq, bk, bv, qb, nullptr, M, 2304, ND, 2304 / 128);

    // band attention (static 48KB LDS, XCD-swizzled grid)
    attn_kernel<<<NB * NH * NCH, 512, 0, stream>>>(qb, kb_, vb_, src, attw, x_bf);

    // FFN: grids 24*64 = 1536 and 6*64 = 384 (both div by 8)
    gemmdb<2><<<(NDFF / 128) * (M / 128), 256, 0, stream>>>(
        x_bf, W1T, b1, b1, b1, hbuf, nullptr, M, NDFF, ND, NDFF / 128);
    gemmdb<3><<<(ND / 128) * (M / 128), 256, 0, stream>>>(
        hbuf, W2T, b2, b2, b2, out, x_bf, M, ND, NDFF, ND / 128);

    // LayerNorm in-place
    ln_kernel<<<M, 256, 0, stream>>>(out, g2, bt2);
}